// Round 16
// baseline (161.863 us; speedup 1.0000x reference)
//
#include <hip/hip_runtime.h>
#include <cmath>

#define NE 2048
#define NN 4096
#define D 256
#define H 8
#define DH 64
#define HD 512
#define MAXREL 10
#define NREL 21
#define NEG_BIG -3.0e38f
#define L2E 1.44269504f

typedef __attribute__((ext_vector_type(8))) short bf16x8;
typedef __attribute__((ext_vector_type(4))) float f32x4;

__device__ inline short f2bf(float x) {
  union { float f; unsigned u; } c; c.f = x;
  unsigned r = (c.u + 0x7FFFu + ((c.u >> 16) & 1u)) >> 16;
  return (short)r;
}
__device__ inline short f2bf_t(float x) {
  return (short)(__float_as_uint(x) >> 16);
}
__device__ inline float bf2f(short s) {
  return __uint_as_float(((unsigned)(unsigned short)s) << 16);
}

__device__ inline void gl_lds16(const void* g, void* l) {
  __builtin_amdgcn_global_load_lds(
      (const __attribute__((address_space(1))) void*)g,
      (__attribute__((address_space(3))) void*)l, 16, 0, 0);
}

// ---------- prep_all: e2 | x2 | maskprep | wprep_q | wprep_kv | wprep_o ----------
__global__ __launch_bounds__(256) void prep_all(
    const float* __restrict__ he, const int* __restrict__ htyp,
    const float* __restrict__ ge, const float* __restrict__ be,
    const float* __restrict__ nf, const int* __restrict__ ntyp,
    const float* __restrict__ gn, const float* __restrict__ bn,
    const int* __restrict__ inc, const float* __restrict__ Wq,
    const float* __restrict__ Wk, const float* __restrict__ Wv,
    const float* __restrict__ Wo,
    short* __restrict__ E2, short* __restrict__ X2,
    unsigned short* __restrict__ maskb, short* __restrict__ Wqf,
    short* __restrict__ Wkf, short* __restrict__ Wvf,
    short* __restrict__ Rf, short* __restrict__ Wof) {
  const int bid = blockIdx.x;
  const int t = threadIdx.x;
  __shared__ float part[4];
  __shared__ float bc[2];
  __shared__ float lnv[D];

  if (bid < NE) {
    const int i = bid;
    const float x = he[(size_t)i * D + t];
    float s = x;
#pragma unroll
    for (int off = 32; off > 0; off >>= 1) s += __shfl_down(s, off);
    if ((t & 63) == 0) part[t >> 6] = s;
    __syncthreads();
    if (t == 0) bc[0] = (part[0] + part[1] + part[2] + part[3]) * (1.0f / D);
    __syncthreads();
    const float mean = bc[0];
    const float dev = x - mean;
    float sq = dev * dev;
#pragma unroll
    for (int off = 32; off > 0; off >>= 1) sq += __shfl_down(sq, off);
    __syncthreads();
    if ((t & 63) == 0) part[t >> 6] = sq;
    __syncthreads();
    if (t == 0) bc[1] = (part[0] + part[1] + part[2] + part[3]) * (1.0f / D);
    __syncthreads();
    const float inv = rsqrtf(bc[1] + 1e-5f);
    const float v = dev * inv * ge[t] + be[t];
    lnv[t] = v;
    __syncthreads();
    const int ht = htyp[i];
    const int slot = (ht == 0) ? 0 : ht - 1;
    const int iin = i & 15, rt = i >> 4;
    {
      const int dd0 = 4 * t;
      const int kt = dd0 >> 5;
      const int lane = ((dd0 >> 2) & 3) * 16 + iin;
      const int e0 = ((dd0 >> 4) & 1) * 4;
      short v4[4];
#pragma unroll
      for (int u = 0; u < 4; ++u)
        v4[u] = ((dd0 >> 8) == slot) ? f2bf(lnv[(dd0 + u) & 255]) : (short)0;
      short* dst = E2 + ((size_t)(rt * 32 + kt) * 64 + lane) * 8 + e0;
      *(short4*)dst = make_short4(v4[0], v4[1], v4[2], v4[3]);
    }
    if (t < 128) {
      const int c0 = 2 * t;
      const int kt = c0 >> 5, kk = c0 & 31;
      const int l = ((kk >> 2) & 3) * 16 + iin;
      const int ee = (kk >> 4) * 4 + (kk & 3);
      short* dst = Rf + ((size_t)(rt * 24 + kt) * 64 + l) * 8 + ee;
      *(short2*)dst = make_short2(f2bf(lnv[c0]), f2bf(lnv[c0 + 1]));
    }
  } else if (bid < NE + NN) {
    const int j = bid - NE;
    const float x = nf[(size_t)j * D + t];
    float s = x;
#pragma unroll
    for (int off = 32; off > 0; off >>= 1) s += __shfl_down(s, off);
    if ((t & 63) == 0) part[t >> 6] = s;
    __syncthreads();
    if (t == 0) bc[0] = (part[0] + part[1] + part[2] + part[3]) * (1.0f / D);
    __syncthreads();
    const float mean = bc[0];
    const float dev = x - mean;
    float sq = dev * dev;
#pragma unroll
    for (int off = 32; off > 0; off >>= 1) sq += __shfl_down(sq, off);
    __syncthreads();
    if ((t & 63) == 0) part[t >> 6] = sq;
    __syncthreads();
    if (t == 0) bc[1] = (part[0] + part[1] + part[2] + part[3]) * (1.0f / D);
    __syncthreads();
    const float inv = rsqrtf(bc[1] + 1e-5f);
    lnv[t] = dev * inv * gn[t] + bn[t];
    __syncthreads();
    const int nt = ntyp[j];
    const int jin = j & 15, rt = j >> 4;
    const int dd0 = 2 * t;
    const int kt = dd0 >> 5;
    const int lane = ((dd0 >> 2) & 3) * 16 + jin;
    const int e0 = ((dd0 >> 4) & 1) * 4 + (dd0 & 3);
    const short v0 = ((dd0 >> 8) == nt) ? f2bf(lnv[dd0 & 255]) : (short)0;
    const short v1 = ((dd0 >> 8) == nt) ? f2bf(lnv[(dd0 + 1) & 255]) : (short)0;
    short* dst = X2 + ((size_t)(rt * 16 + kt) * 64 + lane) * 8 + e0;
    *(short2*)dst = make_short2(v0, v1);
  } else if (bid < NE + NN + NN / 2) {
    const int bb = bid - (NE + NN);
    const int it = t & 127;
    const int gj = bb * 2 + (t >> 7);
    const int* p = inc + (size_t)gj * NE + it * 16;
    unsigned m = 0;
#pragma unroll
    for (int r = 0; r < 16; ++r) m |= (p[r] != 0 ? 1u : 0u) << r;
    maskb[(size_t)it * NN + gj] = (unsigned short)m;
  } else if (bid < NE + NN + NN / 2 + 256) {
    const int bb = bid - (NE + NN + NN / 2);
    const int f = bb * 4 + (t >> 6);
    const int lane = t & 63;
    const int ct = f >> 5, kt = f & 31;
    const int c = ct * 16 + (lane & 15);
    const int khi = (lane >> 4) * 4;
    bf16x8 r;
#pragma unroll
    for (int e = 0; e < 8; ++e) {
      const int kk = (e >> 2) * 16 + khi + (e & 3);
      const int dd = kt * 32 + kk;
      const int sslot = dd >> 8;
      const int tt = (sslot == 0) ? 0 : sslot + 1;
      r[e] = f2bf(Wq[((size_t)tt * 256 + (dd & 255)) * 512 + c]);
    }
    *(bf16x8*)(Wqf + ((size_t)f * 64 + lane) * 8) = r;
  } else if (bid < NE + NN + NN / 2 + 256 + 128) {
    const int bb = bid - (NE + NN + NN / 2 + 256);
    const int f = bb * 4 + (t >> 6);
    const int lane = t & 63;
    const int ct = f >> 4, kt = f & 15;
    const int c = ct * 16 + (lane & 15);
    const int khi = (lane >> 4) * 4;
    bf16x8 rk, rv;
#pragma unroll
    for (int e = 0; e < 8; ++e) {
      const int kk = (e >> 2) * 16 + khi + (e & 3);
      const int dd = kt * 32 + kk;
      rk[e] = f2bf(Wk[(size_t)dd * 512 + c]);
      rv[e] = f2bf(Wv[(size_t)dd * 512 + c]);
    }
    *(bf16x8*)(Wkf + ((size_t)f * 64 + lane) * 8) = rk;
    *(bf16x8*)(Wvf + ((size_t)f * 64 + lane) * 8) = rv;
  } else {
    const int bb = bid - (NE + NN + NN / 2 + 256 + 128);
    const int f = bb * 4 + (t >> 6);   // 0..383
    const int lane = t & 63;
    const int ct = f / 24, kt = f - ct * 24;
    const int c = ct * 16 + (lane & 15);
    const int khi = (lane >> 4) * 4;
    bf16x8 r;
#pragma unroll
    for (int e = 0; e < 8; ++e) {
      const int kk = (e >> 2) * 16 + khi + (e & 3);
      const int dd = kt * 32 + kk;
      r[e] = f2bf(Wo[(size_t)dd * 256 + c]);
    }
    *(bf16x8*)(Wof + ((size_t)f * 64 + lane) * 8) = r;
  }
}

// ---------- proj_all: projq (bid<512) | projkv (bid>=512) ----------
__global__ __launch_bounds__(256) void proj_all(
    const short* __restrict__ E2, const short* __restrict__ Wqf,
    short* __restrict__ Qp, const short* __restrict__ X2,
    const short* __restrict__ Wkf, const short* __restrict__ Wvf,
    short* __restrict__ Kp, short* __restrict__ Vp) {
  const int tid = threadIdx.x;
  const int w = tid >> 6, lane = tid & 63;
  __shared__ __align__(16) short tiles[2][12 * 512];

  if (blockIdx.x < 512) {
    const int RT0 = (blockIdx.x & 63) * 2;
    const int CT0 = (blockIdx.x >> 6) * 4;

#define QSTAGE(buf, ks)                                                        \
  do {                                                                         \
    const int rtl_ = w >> 1, ktl_ = w & 1;                                     \
    gl_lds16(E2 + ((size_t)((RT0 + rtl_) * 32 + (ks) * 2 + ktl_) * 64 + lane) * 8, \
             &tiles[buf][w * 512 + lane * 8]);                                 \
    gl_lds16(Wqf + ((size_t)((CT0 + (w >> 1)) * 32 + (ks) * 2 + (w & 1)) * 64 + lane) * 8, \
             &tiles[buf][(4 + w) * 512 + lane * 8]);                           \
    gl_lds16(Wqf + ((size_t)((CT0 + 2 + (w >> 1)) * 32 + (ks) * 2 + (w & 1)) * 64 + lane) * 8, \
             &tiles[buf][(8 + w) * 512 + lane * 8]);                           \
  } while (0)

    const int itl = w >> 1, ctp = w & 1;
    f32x4 acc[2] = {{0.f, 0.f, 0.f, 0.f}, {0.f, 0.f, 0.f, 0.f}};

    QSTAGE(0, 0);
    for (int ks = 0; ks < 16; ++ks) {
      const int cb = ks & 1;
      if (ks + 1 < 16) {
        QSTAGE(cb ^ 1, ks + 1);
        asm volatile("s_waitcnt vmcnt(3)" ::: "memory");
      } else {
        asm volatile("s_waitcnt vmcnt(0)" ::: "memory");
      }
      __builtin_amdgcn_s_barrier();
#pragma unroll
      for (int ktl = 0; ktl < 2; ++ktl) {
        const bf16x8 ef = *(const bf16x8*)&tiles[cb][(itl * 2 + ktl) * 512 + lane * 8];
#pragma unroll
        for (int ci = 0; ci < 2; ++ci) {
          const int ctl = ctp * 2 + ci;
          const bf16x8 qw = *(const bf16x8*)&tiles[cb][(4 + ctl * 2 + ktl) * 512 + lane * 8];
          acc[ci] = __builtin_amdgcn_mfma_f32_16x16x32_bf16(qw, ef, acc[ci], 0, 0, 0);
        }
      }
      __builtin_amdgcn_s_barrier();
    }

    const int it_g = RT0 + itl;
    const int ct_even = CT0 + ctp * 2;
    const int hh = ct_even >> 2, kc = (ct_even >> 1) & 1;
    bf16x8 fr;
#pragma unroll
    for (int r = 0; r < 4; ++r) { fr[r] = f2bf(acc[0][r]); fr[4 + r] = f2bf(acc[1][r]); }
    *(bf16x8*)(Qp + (((size_t)hh * (NE / 16) + it_g) * 2 + kc) * 512 + (size_t)lane * 8) = fr;
  } else {
    const int bb = blockIdx.x - 512;
    const int RT0 = (bb & 63) * 4;
    const int CT0 = (bb >> 6) * 4;

#define KVSTAGE(buf, kt)                                                       \
  do {                                                                         \
    gl_lds16(X2 + ((size_t)((RT0 + w) * 16 + (kt)) * 64 + lane) * 8,           \
             &tiles[buf][w * 512 + lane * 8]);                                 \
    gl_lds16(Wkf + ((size_t)((CT0 + w) * 16 + (kt)) * 64 + lane) * 8,          \
             &tiles[buf][(4 + w) * 512 + lane * 8]);                           \
    gl_lds16(Wvf + ((size_t)((CT0 + w) * 16 + (kt)) * 64 + lane) * 8,          \
             &tiles[buf][(8 + w) * 512 + lane * 8]);                           \
  } while (0)

    const int wr = w >> 1, wc = w & 1;
    f32x4 accK[2][2], accV[2][2];
#pragma unroll
    for (int a = 0; a < 2; ++a)
#pragma unroll
      for (int b = 0; b < 2; ++b) {
        accK[a][b] = (f32x4){0.f, 0.f, 0.f, 0.f};
        accV[a][b] = (f32x4){0.f, 0.f, 0.f, 0.f};
      }

    KVSTAGE(0, 0);
    for (int kt = 0; kt < 16; ++kt) {
      const int cb = kt & 1;
      if (kt + 1 < 16) {
        KVSTAGE(cb ^ 1, kt + 1);
        asm volatile("s_waitcnt vmcnt(3)" ::: "memory");
      } else {
        asm volatile("s_waitcnt vmcnt(0)" ::: "memory");
      }
      __builtin_amdgcn_s_barrier();
      bf16x8 xf[2], kf[2], vf[2];
#pragma unroll
      for (int p = 0; p < 2; ++p) {
        xf[p] = *(const bf16x8*)&tiles[cb][(wr * 2 + p) * 512 + lane * 8];
        kf[p] = *(const bf16x8*)&tiles[cb][(4 + wc * 2 + p) * 512 + lane * 8];
        vf[p] = *(const bf16x8*)&tiles[cb][(8 + wc * 2 + p) * 512 + lane * 8];
      }
#pragma unroll
      for (int ci = 0; ci < 2; ++ci)
#pragma unroll
        for (int ji = 0; ji < 2; ++ji) {
          accK[ci][ji] = __builtin_amdgcn_mfma_f32_16x16x32_bf16(kf[ci], xf[ji], accK[ci][ji], 0, 0, 0);
          accV[ji][ci] = __builtin_amdgcn_mfma_f32_16x16x32_bf16(xf[ji], vf[ci], accV[ji][ci], 0, 0, 0);
        }
      __builtin_amdgcn_s_barrier();
    }

    const int ct_even = CT0 + wc * 2;
    const int hh = ct_even >> 2, kc = (ct_even >> 1) & 1;
#pragma unroll
    for (int ji = 0; ji < 2; ++ji) {
      const int jt16 = RT0 + wr * 2 + ji;
      bf16x8 fr;
#pragma unroll
      for (int r = 0; r < 4; ++r) { fr[r] = f2bf(accK[0][ji][r]); fr[4 + r] = f2bf(accK[1][ji][r]); }
      *(bf16x8*)(Kp + (((((size_t)hh * 64 + (jt16 >> 2)) * 4 + (jt16 & 3)) * 2 + kc) * 512) + (size_t)lane * 8) = fr;
    }
    const int jt_even = RT0 + wr * 2;
    const int jt64 = jt_even >> 2, kcv = (jt_even >> 1) & 1;
#pragma unroll
    for (int ci = 0; ci < 2; ++ci) {
      const int ctg = CT0 + wc * 2 + ci;
      const int hhv = ctg >> 2, dh16 = ctg & 3;
      bf16x8 fr;
#pragma unroll
      for (int r = 0; r < 4; ++r) { fr[r] = f2bf(accV[0][ci][r]); fr[4 + r] = f2bf(accV[1][ci][r]); }
      *(bf16x8*)(Vp + ((((size_t)hhv * 64 + jt64) * 4 + dh16) * 2 + kcv) * 512 + (size_t)lane * 8) = fr;
    }
  }
}

// ---------- fused MFMA attention: direct L2 reads, NO LDS staging, NO barriers ----------
// K/V per (h,split) is 128 KB — L2-resident across the 32 i-blocks (m169: don't
// stage what L2-fits). Each wave runs fully independent; stores stream ungated.
__global__ __launch_bounds__(256) void attn_mfma(
    const short* __restrict__ Qp, const short* __restrict__ Kp,
    const short* __restrict__ Vp, const unsigned short* __restrict__ maskb,
    const float* __restrict__ rel_emb, float* __restrict__ scores,
    short* __restrict__ po, float* __restrict__ pm, float* __restrict__ pl,
    int tps) {
  const int h = blockIdx.y;
  const int split = blockIdx.z;
  const int tid = threadIdx.x;
  const int lane = tid & 63;
  const int i0w = blockIdx.x * 64 + (tid >> 6) * 16;
  const int gi = i0w + (lane & 15);
  const int gi15 = lane & 15;
  const int lhi4 = (lane >> 4) * 4;
  const int jt0 = split * tps;
  const int itw = i0w >> 4;

  __shared__ float relb[NREL];
  if (tid < NREL) relb[tid] = rel_emb[tid * H + h];
  __syncthreads();

  const size_t qbase = (((size_t)h * (NE / 16) + itw) * 2) * 512 + (size_t)lane * 8;
  const bf16x8 qf0 = *(const bf16x8*)(Qp + qbase);
  const bf16x8 qf1 = *(const bf16x8*)(Qp + qbase + 512);

  const short* kgh = Kp + (size_t)h * 64 * 4096 + lane * 8;
  const short* vgh = Vp + (size_t)h * 64 * 4096 + lane * 8;
  const unsigned short* mgh = maskb + (size_t)itw * NN;

  float m_run = -INFINITY, l_run = 0.f;
  f32x4 o0 = {0.f, 0.f, 0.f, 0.f}, o1 = o0, o2 = o0, o3 = o0;

  for (int t = 0; t < tps; ++t) {
    const int jb = jt0 + t;
    const size_t toff = (size_t)jb * 4096;
    const int j0 = jb * 64;
    const float bc0 = relb[0], bc20 = relb[20];
    const bool allhi = (j0 > i0w + 15 + MAXREL);
    const bool alllo = (j0 + 63 < i0w - MAXREL);

    // mask words for all 4 sub-tiles (independent 8B loads, L2/L3)
    uint2 mw[4];
#pragma unroll
    for (int ms = 0; ms < 4; ++ms)
      mw[ms] = *(const uint2*)(mgh + toff / 64 + ms * 16 + lhi4);

    float lg[4][4];
#pragma unroll
    for (int ms = 0; ms < 4; ++ms) {
      const bf16x8 ka = *(const bf16x8*)(kgh + toff + (ms * 2 + 0) * 512);
      const bf16x8 kb = *(const bf16x8*)(kgh + toff + (ms * 2 + 1) * 512);
      f32x4 sf = {0.f, 0.f, 0.f, 0.f};
      sf = __builtin_amdgcn_mfma_f32_16x16x32_bf16(ka, qf0, sf, 0, 0, 0);
      sf = __builtin_amdgcn_mfma_f32_16x16x32_bf16(kb, qf1, sf, 0, 0, 0);
      const int jb0 = j0 + ms * 16 + lhi4;
#pragma unroll
      for (int r = 0; r < 4; ++r) {
        const int gj = jb0 + r;
        float bias;
        if (allhi) bias = bc0;
        else if (alllo) bias = bc20;
        else {
          int dd = gi - gj;
          dd = dd < -MAXREL ? -MAXREL : (dd > MAXREL ? MAXREL : dd);
          bias = relb[dd + MAXREL];
        }
        const unsigned word = (r < 2) ? mw[ms].x : mw[ms].y;
        const unsigned ok = (word >> ((r & 1) * 16 + gi15)) & 1u;
        lg[ms][r] = ok ? fmaf(sf[r], 0.125f, bias) : -INFINITY;
      }
      f32x4 sv;
      sv[0] = fmaxf(lg[ms][0], NEG_BIG);
      sv[1] = fmaxf(lg[ms][1], NEG_BIG);
      sv[2] = fmaxf(lg[ms][2], NEG_BIG);
      sv[3] = fmaxf(lg[ms][3], NEG_BIG);
      *(f32x4*)(scores + ((size_t)h * NE + gi) * NN + jb0) = sv;
    }

    float tmax = -INFINITY;
#pragma unroll
    for (int ms = 0; ms < 4; ++ms)
#pragma unroll
      for (int r = 0; r < 4; ++r) tmax = fmaxf(tmax, lg[ms][r]);
    tmax = fmaxf(tmax, __shfl_xor(tmax, 16));
    tmax = fmaxf(tmax, __shfl_xor(tmax, 32));
    const float mnew = fmaxf(m_run, tmax);
    const float rs = (m_run == mnew) ? 1.f : exp2f((m_run - mnew) * L2E);
    float p[4][4];
    float ps = 0.f;
#pragma unroll
    for (int ms = 0; ms < 4; ++ms)
#pragma unroll
      for (int r = 0; r < 4; ++r) {
        const float v = lg[ms][r];
        const float pe = (v == -INFINITY) ? 0.f : exp2f((v - mnew) * L2E);
        p[ms][r] = pe;
        ps += pe;
      }
    l_run = l_run * rs + ps;
    m_run = mnew;
    if (!__all(rs == 1.0f)) { o0 *= rs; o1 *= rs; o2 *= rs; o3 *= rs; }

    bf16x8 pb0, pb1;
    pb0[0] = f2bf_t(p[0][0]); pb0[1] = f2bf_t(p[0][1]); pb0[2] = f2bf_t(p[0][2]); pb0[3] = f2bf_t(p[0][3]);
    pb0[4] = f2bf_t(p[1][0]); pb0[5] = f2bf_t(p[1][1]); pb0[6] = f2bf_t(p[1][2]); pb0[7] = f2bf_t(p[1][3]);
    pb1[0] = f2bf_t(p[2][0]); pb1[1] = f2bf_t(p[2][1]); pb1[2] = f2bf_t(p[2][2]); pb1[3] = f2bf_t(p[2][3]);
    pb1[4] = f2bf_t(p[3][0]); pb1[5] = f2bf_t(p[3][1]); pb1[6] = f2bf_t(p[3][2]); pb1[7] = f2bf_t(p[3][3]);

    o0 = __builtin_amdgcn_mfma_f32_16x16x32_bf16(*(const bf16x8*)(vgh + toff + 0 * 512), pb0, o0, 0, 0, 0);
    o0 = __builtin_amdgcn_mfma_f32_16x16x32_bf16(*(const bf16x8*)(vgh + toff + 1 * 512), pb1, o0, 0, 0, 0);
    o1 = __builtin_amdgcn_mfma_f32_16x16x32_bf16(*(const bf16x8*)(vgh + toff + 2 * 512), pb0, o1, 0, 0, 0);
    o1 = __builtin_amdgcn_mfma_f32_16x16x32_bf16(*(const bf16x8*)(vgh + toff + 3 * 512), pb1, o1, 0, 0, 0);
    o2 = __builtin_amdgcn_mfma_f32_16x16x32_bf16(*(const bf16x8*)(vgh + toff + 4 * 512), pb0, o2, 0, 0, 0);
    o2 = __builtin_amdgcn_mfma_f32_16x16x32_bf16(*(const bf16x8*)(vgh + toff + 5 * 512), pb1, o2, 0, 0, 0);
    o3 = __builtin_amdgcn_mfma_f32_16x16x32_bf16(*(const bf16x8*)(vgh + toff + 6 * 512), pb0, o3, 0, 0, 0);
    o3 = __builtin_amdgcn_mfma_f32_16x16x32_bf16(*(const bf16x8*)(vgh + toff + 7 * 512), pb1, o3, 0, 0, 0);
  }

  l_run += __shfl_xor(l_run, 16);
  l_run += __shfl_xor(l_run, 32);
  const size_t pbase = ((size_t)split * H + h) * NE + gi;
  if (lane < 16) { pm[pbase] = m_run; pl[pbase] = l_run; }
  short* pob = po + pbase * DH + lhi4;
  *(short4*)(pob +  0) = make_short4(f2bf(o0[0]), f2bf(o0[1]), f2bf(o0[2]), f2bf(o0[3]));
  *(short4*)(pob + 16) = make_short4(f2bf(o1[0]), f2bf(o1[1]), f2bf(o1[2]), f2bf(o1[3]));
  *(short4*)(pob + 32) = make_short4(f2bf(o2[0]), f2bf(o2[1]), f2bf(o2[2]), f2bf(o2[3]));
  *(short4*)(pob + 48) = make_short4(f2bf(o3[0]), f2bf(o3[1]), f2bf(o3[2]), f2bf(o3[3]));
}

// ---------- combine: merge split partials + silu -> Rf att-part (bf16 frags) ----------
__global__ __launch_bounds__(256) void combine_kernel(
    const short* __restrict__ po, const float* __restrict__ pm,
    const float* __restrict__ pl, short* __restrict__ Rf, int splits) {
  const int g = blockIdx.x * 8 + (threadIdx.x >> 5);
  const int dh0 = (threadIdx.x & 31) * 2;
  const int h = g >> 11;
  const int i = g & (NE - 1);
  float M = -INFINITY;
  for (int s = 0; s < splits; ++s)
    M = fmaxf(M, pm[((size_t)s * H + h) * NE + i]);
  float L = 0.f, o0 = 0.f, o1 = 0.f;
  for (int s = 0; s < splits; ++s) {
    const size_t pb = ((size_t)s * H + h) * NE + i;
    const float ms = pm[pb];
    if (ms > -INFINITY) {
      const float wgt = exp2f((ms - M) * L2E);
      L += wgt * pl[pb];
      const short2 ov = *(const short2*)&po[pb * DH + dh0];
      o0 += wgt * bf2f(ov.x);
      o1 += wgt * bf2f(ov.y);
    }
  }
  const float a0 = o0 / L, a1 = o1 / L;
  const float s0 = a0 / (1.f + expf(-a0));
  const float s1 = a1 / (1.f + expf(-a1));
  const int col = 256 + h * DH + dh0;
  const int kt = col >> 5, kk = col & 31;
  const int l = ((kk >> 2) & 3) * 16 + (i & 15);
  const int ee = (kk >> 4) * 4 + (kk & 3);
  short* dst = Rf + ((size_t)((i >> 4) * 24 + kt) * 64 + l) * 8 + ee;
  *(short2*)dst = make_short2(f2bf(s0), f2bf(s1));
}

// ---------- final GEMM (MFMA): out = Rf[2048x768] @ Wo + bo ----------
__global__ __launch_bounds__(256) void final_mfma(
    const short* __restrict__ Rf, const short* __restrict__ Wof,
    const float* __restrict__ bo, float* __restrict__ out) {
  const int tid = threadIdx.x;
  const int w = tid >> 6, lane = tid & 63;
  const int RT0 = blockIdx.x * 2;
  const int CT0 = blockIdx.y * 4;
  __shared__ __align__(16) short tiles[2][12 * 512];

#define FSTAGE(buf, ks)                                                        \
  do {                                                                         \
    const int rtl_ = w >> 1, ktl_ = w & 1;                                     \
    gl_lds16(Rf + ((size_t)((RT0 + rtl_) * 24 + (ks) * 2 + ktl_) * 64 + lane) * 8, \
             &tiles[buf][w * 512 + lane * 8]);                                 \
    gl_lds16(Wof + ((size_t)((CT0 + (w >> 1)) * 24 + (ks) * 2 + (w & 1)) * 64 + lane) * 8, \
             &tiles[buf][(4 + w) * 512 + lane * 8]);                           \
    gl_lds16(Wof + ((size_t)((CT0 + 2 + (w >> 1)) * 24 + (ks) * 2 + (w & 1)) * 64 + lane) * 8, \
             &tiles[buf][(8 + w) * 512 + lane * 8]);                           \
  } while (0)

  const int itl = w >> 1, ctp = w & 1;
  f32x4 acc[2] = {{0.f, 0.f, 0.f, 0.f}, {0.f, 0.f, 0.f, 0.f}};

  FSTAGE(0, 0);
  for (int ks = 0; ks < 12; ++ks) {
    const int cb = ks & 1;
    if (ks + 1 < 12) {
      FSTAGE(cb ^ 1, ks + 1);
      asm volatile("s_waitcnt vmcnt(3)" ::: "memory");
    } else {
      asm volatile("s_waitcnt vmcnt(0)" ::: "memory");
    }
    __builtin_amdgcn_s_barrier();
#pragma unroll
    for (int ktl = 0; ktl < 2; ++ktl) {
      const bf16x8 rf = *(const bf16x8*)&tiles[cb][(itl * 2 + ktl) * 512 + lane * 8];
#pragma unroll
      for (int ci = 0; ci < 2; ++ci) {
        const int ctl = ctp * 2 + ci;
        const bf16x8 wf = *(const bf16x8*)&tiles[cb][(4 + ctl * 2 + ktl) * 512 + lane * 8];
        acc[ci] = __builtin_amdgcn_mfma_f32_16x16x32_bf16(wf, rf, acc[ci], 0, 0, 0);
      }
    }
    __builtin_amdgcn_s_barrier();
  }

  const int gi = (RT0 + itl) * 16 + (lane & 15);
  const int lhi4 = (lane >> 4) * 4;
#pragma unroll
  for (int ci = 0; ci < 2; ++ci) {
    const int c0 = (CT0 + ctp * 2 + ci) * 16 + lhi4;
    float4 o;
    o.x = acc[ci][0] + bo[c0];
    o.y = acc[ci][1] + bo[c0 + 1];
    o.z = acc[ci][2] + bo[c0 + 2];
    o.w = acc[ci][3] + bo[c0 + 3];
    *(float4*)(out + (size_t)gi * D + c0) = o;
  }
}

extern "C" void kernel_launch(void* const* d_in, const int* in_sizes, int n_in,
                              void* d_out, int out_size, void* d_ws, size_t ws_size,
                              hipStream_t stream) {
  (void)in_sizes; (void)n_in; (void)out_size;
  const float* he   = (const float*)d_in[0];
  const float* nf   = (const float*)d_in[1];
  const int*   inc  = (const int*)d_in[2];
  const int*   ntyp = (const int*)d_in[3];
  const int*   htyp = (const int*)d_in[4];
  const float* Wq   = (const float*)d_in[5];
  const float* Wk   = (const float*)d_in[6];
  const float* Wv   = (const float*)d_in[7];
  const float* Wo   = (const float*)d_in[8];
  const float* bo   = (const float*)d_in[9];
  const float* ge   = (const float*)d_in[10];
  const float* be   = (const float*)d_in[11];
  const float* gn   = (const float*)d_in[12];
  const float* bn   = (const float*)d_in[13];
  const float* rel  = (const float*)d_in[14];

  float* outf = (float*)d_out;
  float* outs = outf + (size_t)NE * D;

  short* X2   = (short*)d_ws;
  short* E2   = X2 + (size_t)NN * 512;
  short* Wkf  = E2 + (size_t)NE * 1024;
  short* Wvf  = Wkf + (size_t)512 * 512;
  short* Wqf  = Wvf + (size_t)512 * 512;
  short* Qp   = Wqf + (size_t)512 * 1024;
  short* Kp   = Qp + (size_t)NE * HD;
  short* Vp   = Kp + (size_t)NN * HD;
  short* Rf   = Vp + (size_t)NN * HD;
  short* Wof  = Rf + (size_t)128 * 24 * 512;
  unsigned short* maskb = (unsigned short*)(Wof + (size_t)384 * 512);
  short* po   = (short*)(maskb + (size_t)(NE / 16) * NN);

  const size_t used_bytes = (size_t)((char*)po - (char*)d_ws);
  int splits = 8;
  while (splits > 1 &&
         used_bytes + (size_t)splits * H * NE * (DH * 2 + 8) > ws_size)
    splits >>= 1;
  float* pm = (float*)(po + (size_t)splits * H * NE * DH);
  float* pl = pm + (size_t)splits * H * NE;
  const int tps = NN / 64 / splits;

  prep_all<<<NE + NN + NN / 2 + 256 + 128 + 96, 256, 0, stream>>>(
      he, htyp, ge, be, nf, ntyp, gn, bn, inc, Wq, Wk, Wv, Wo,
      E2, X2, maskb, Wqf, Wkf, Wvf, Rf, Wof);
  proj_all<<<1024, 256, 0, stream>>>(E2, Wqf, Qp, X2, Wkf, Wvf, Kp, Vp);
  attn_mfma<<<dim3(NE / 64, H, splits), 256, 0, stream>>>(
      Qp, Kp, Vp, maskb, rel, outs, po, pm, pl, tps);
  combine_kernel<<<NE * H / 8, 256, 0, stream>>>(po, pm, pl, Rf, splits);
  final_mfma<<<dim3(64, 4), 256, 0, stream>>>(Rf, Wof, bo, outf);
}

// Round 17
// 150.733 us; speedup vs baseline: 1.0738x; 1.0738x over previous
//
#include <hip/hip_runtime.h>
#include <cmath>

#define NE 2048
#define NN 4096
#define D 256
#define H 8
#define DH 64
#define HD 512
#define MAXREL 10
#define NREL 21
#define NEG_BIG -3.0e38f
#define L2E 1.44269504f

typedef __attribute__((ext_vector_type(8))) short bf16x8;
typedef __attribute__((ext_vector_type(4))) float f32x4;

__device__ inline short f2bf(float x) {
  union { float f; unsigned u; } c; c.f = x;
  unsigned r = (c.u + 0x7FFFu + ((c.u >> 16) & 1u)) >> 16;
  return (short)r;
}
__device__ inline short f2bf_t(float x) {
  return (short)(__float_as_uint(x) >> 16);
}
__device__ inline float bf2f(short s) {
  return __uint_as_float(((unsigned)(unsigned short)s) << 16);
}

__device__ inline void gl_lds16(const void* g, void* l) {
  __builtin_amdgcn_global_load_lds(
      (const __attribute__((address_space(1))) void*)g,
      (__attribute__((address_space(3))) void*)l, 16, 0, 0);
}

// ---------- prep_all: e2 | x2 | maskprep | wprep_q | wprep_kv | wprep_o ----------
__global__ __launch_bounds__(256) void prep_all(
    const float* __restrict__ he, const int* __restrict__ htyp,
    const float* __restrict__ ge, const float* __restrict__ be,
    const float* __restrict__ nf, const int* __restrict__ ntyp,
    const float* __restrict__ gn, const float* __restrict__ bn,
    const int* __restrict__ inc, const float* __restrict__ Wq,
    const float* __restrict__ Wk, const float* __restrict__ Wv,
    const float* __restrict__ Wo,
    short* __restrict__ E2, short* __restrict__ X2,
    unsigned short* __restrict__ maskb, short* __restrict__ Wqf,
    short* __restrict__ Wkf, short* __restrict__ Wvf,
    short* __restrict__ Rf, short* __restrict__ Wof) {
  const int bid = blockIdx.x;
  const int t = threadIdx.x;
  __shared__ float part[4];
  __shared__ float bc[2];
  __shared__ float lnv[D];

  if (bid < NE) {
    const int i = bid;
    const float x = he[(size_t)i * D + t];
    float s = x;
#pragma unroll
    for (int off = 32; off > 0; off >>= 1) s += __shfl_down(s, off);
    if ((t & 63) == 0) part[t >> 6] = s;
    __syncthreads();
    if (t == 0) bc[0] = (part[0] + part[1] + part[2] + part[3]) * (1.0f / D);
    __syncthreads();
    const float mean = bc[0];
    const float dev = x - mean;
    float sq = dev * dev;
#pragma unroll
    for (int off = 32; off > 0; off >>= 1) sq += __shfl_down(sq, off);
    __syncthreads();
    if ((t & 63) == 0) part[t >> 6] = sq;
    __syncthreads();
    if (t == 0) bc[1] = (part[0] + part[1] + part[2] + part[3]) * (1.0f / D);
    __syncthreads();
    const float inv = rsqrtf(bc[1] + 1e-5f);
    const float v = dev * inv * ge[t] + be[t];
    lnv[t] = v;
    __syncthreads();
    const int ht = htyp[i];
    const int slot = (ht == 0) ? 0 : ht - 1;
    const int iin = i & 15, rt = i >> 4;
    {
      const int dd0 = 4 * t;
      const int kt = dd0 >> 5;
      const int lane = ((dd0 >> 2) & 3) * 16 + iin;
      const int e0 = ((dd0 >> 4) & 1) * 4;
      short v4[4];
#pragma unroll
      for (int u = 0; u < 4; ++u)
        v4[u] = ((dd0 >> 8) == slot) ? f2bf(lnv[(dd0 + u) & 255]) : (short)0;
      short* dst = E2 + ((size_t)(rt * 32 + kt) * 64 + lane) * 8 + e0;
      *(short4*)dst = make_short4(v4[0], v4[1], v4[2], v4[3]);
    }
    if (t < 128) {
      const int c0 = 2 * t;
      const int kt = c0 >> 5, kk = c0 & 31;
      const int l = ((kk >> 2) & 3) * 16 + iin;
      const int ee = (kk >> 4) * 4 + (kk & 3);
      short* dst = Rf + ((size_t)(rt * 24 + kt) * 64 + l) * 8 + ee;
      *(short2*)dst = make_short2(f2bf(lnv[c0]), f2bf(lnv[c0 + 1]));
    }
  } else if (bid < NE + NN) {
    const int j = bid - NE;
    const float x = nf[(size_t)j * D + t];
    float s = x;
#pragma unroll
    for (int off = 32; off > 0; off >>= 1) s += __shfl_down(s, off);
    if ((t & 63) == 0) part[t >> 6] = s;
    __syncthreads();
    if (t == 0) bc[0] = (part[0] + part[1] + part[2] + part[3]) * (1.0f / D);
    __syncthreads();
    const float mean = bc[0];
    const float dev = x - mean;
    float sq = dev * dev;
#pragma unroll
    for (int off = 32; off > 0; off >>= 1) sq += __shfl_down(sq, off);
    __syncthreads();
    if ((t & 63) == 0) part[t >> 6] = sq;
    __syncthreads();
    if (t == 0) bc[1] = (part[0] + part[1] + part[2] + part[3]) * (1.0f / D);
    __syncthreads();
    const float inv = rsqrtf(bc[1] + 1e-5f);
    lnv[t] = dev * inv * gn[t] + bn[t];
    __syncthreads();
    const int nt = ntyp[j];
    const int jin = j & 15, rt = j >> 4;
    const int dd0 = 2 * t;
    const int kt = dd0 >> 5;
    const int lane = ((dd0 >> 2) & 3) * 16 + jin;
    const int e0 = ((dd0 >> 4) & 1) * 4 + (dd0 & 3);
    const short v0 = ((dd0 >> 8) == nt) ? f2bf(lnv[dd0 & 255]) : (short)0;
    const short v1 = ((dd0 >> 8) == nt) ? f2bf(lnv[(dd0 + 1) & 255]) : (short)0;
    short* dst = X2 + ((size_t)(rt * 16 + kt) * 64 + lane) * 8 + e0;
    *(short2*)dst = make_short2(v0, v1);
  } else if (bid < NE + NN + NN / 2) {
    const int bb = bid - (NE + NN);
    const int it = t & 127;
    const int gj = bb * 2 + (t >> 7);
    const int* p = inc + (size_t)gj * NE + it * 16;
    unsigned m = 0;
#pragma unroll
    for (int r = 0; r < 16; ++r) m |= (p[r] != 0 ? 1u : 0u) << r;
    maskb[(size_t)it * NN + gj] = (unsigned short)m;
  } else if (bid < NE + NN + NN / 2 + 256) {
    const int bb = bid - (NE + NN + NN / 2);
    const int f = bb * 4 + (t >> 6);
    const int lane = t & 63;
    const int ct = f >> 5, kt = f & 31;
    const int c = ct * 16 + (lane & 15);
    const int khi = (lane >> 4) * 4;
    bf16x8 r;
#pragma unroll
    for (int e = 0; e < 8; ++e) {
      const int kk = (e >> 2) * 16 + khi + (e & 3);
      const int dd = kt * 32 + kk;
      const int sslot = dd >> 8;
      const int tt = (sslot == 0) ? 0 : sslot + 1;
      r[e] = f2bf(Wq[((size_t)tt * 256 + (dd & 255)) * 512 + c]);
    }
    *(bf16x8*)(Wqf + ((size_t)f * 64 + lane) * 8) = r;
  } else if (bid < NE + NN + NN / 2 + 256 + 128) {
    const int bb = bid - (NE + NN + NN / 2 + 256);
    const int f = bb * 4 + (t >> 6);
    const int lane = t & 63;
    const int ct = f >> 4, kt = f & 15;
    const int c = ct * 16 + (lane & 15);
    const int khi = (lane >> 4) * 4;
    bf16x8 rk, rv;
#pragma unroll
    for (int e = 0; e < 8; ++e) {
      const int kk = (e >> 2) * 16 + khi + (e & 3);
      const int dd = kt * 32 + kk;
      rk[e] = f2bf(Wk[(size_t)dd * 512 + c]);
      rv[e] = f2bf(Wv[(size_t)dd * 512 + c]);
    }
    *(bf16x8*)(Wkf + ((size_t)f * 64 + lane) * 8) = rk;
    *(bf16x8*)(Wvf + ((size_t)f * 64 + lane) * 8) = rv;
  } else {
    const int bb = bid - (NE + NN + NN / 2 + 256 + 128);
    const int f = bb * 4 + (t >> 6);   // 0..383
    const int lane = t & 63;
    const int ct = f / 24, kt = f - ct * 24;
    const int c = ct * 16 + (lane & 15);
    const int khi = (lane >> 4) * 4;
    bf16x8 r;
#pragma unroll
    for (int e = 0; e < 8; ++e) {
      const int kk = (e >> 2) * 16 + khi + (e & 3);
      const int dd = kt * 32 + kk;
      r[e] = f2bf(Wo[(size_t)dd * 256 + c]);
    }
    *(bf16x8*)(Wof + ((size_t)f * 64 + lane) * 8) = r;
  }
}

// ---------- proj_all: projq (bid<512) | projkv (bid>=512) ----------
__global__ __launch_bounds__(256) void proj_all(
    const short* __restrict__ E2, const short* __restrict__ Wqf,
    short* __restrict__ Qp, const short* __restrict__ X2,
    const short* __restrict__ Wkf, const short* __restrict__ Wvf,
    short* __restrict__ Kp, short* __restrict__ Vp) {
  const int tid = threadIdx.x;
  const int w = tid >> 6, lane = tid & 63;
  __shared__ __align__(16) short tiles[2][12 * 512];

  if (blockIdx.x < 512) {
    const int RT0 = (blockIdx.x & 63) * 2;
    const int CT0 = (blockIdx.x >> 6) * 4;

#define QSTAGE(buf, ks)                                                        \
  do {                                                                         \
    const int rtl_ = w >> 1, ktl_ = w & 1;                                     \
    gl_lds16(E2 + ((size_t)((RT0 + rtl_) * 32 + (ks) * 2 + ktl_) * 64 + lane) * 8, \
             &tiles[buf][w * 512 + lane * 8]);                                 \
    gl_lds16(Wqf + ((size_t)((CT0 + (w >> 1)) * 32 + (ks) * 2 + (w & 1)) * 64 + lane) * 8, \
             &tiles[buf][(4 + w) * 512 + lane * 8]);                           \
    gl_lds16(Wqf + ((size_t)((CT0 + 2 + (w >> 1)) * 32 + (ks) * 2 + (w & 1)) * 64 + lane) * 8, \
             &tiles[buf][(8 + w) * 512 + lane * 8]);                           \
  } while (0)

    const int itl = w >> 1, ctp = w & 1;
    f32x4 acc[2] = {{0.f, 0.f, 0.f, 0.f}, {0.f, 0.f, 0.f, 0.f}};

    QSTAGE(0, 0);
    for (int ks = 0; ks < 16; ++ks) {
      const int cb = ks & 1;
      if (ks + 1 < 16) {
        QSTAGE(cb ^ 1, ks + 1);
        asm volatile("s_waitcnt vmcnt(3)" ::: "memory");
      } else {
        asm volatile("s_waitcnt vmcnt(0)" ::: "memory");
      }
      __builtin_amdgcn_s_barrier();
#pragma unroll
      for (int ktl = 0; ktl < 2; ++ktl) {
        const bf16x8 ef = *(const bf16x8*)&tiles[cb][(itl * 2 + ktl) * 512 + lane * 8];
#pragma unroll
        for (int ci = 0; ci < 2; ++ci) {
          const int ctl = ctp * 2 + ci;
          const bf16x8 qw = *(const bf16x8*)&tiles[cb][(4 + ctl * 2 + ktl) * 512 + lane * 8];
          acc[ci] = __builtin_amdgcn_mfma_f32_16x16x32_bf16(qw, ef, acc[ci], 0, 0, 0);
        }
      }
      __builtin_amdgcn_s_barrier();
    }

    const int it_g = RT0 + itl;
    const int ct_even = CT0 + ctp * 2;
    const int hh = ct_even >> 2, kc = (ct_even >> 1) & 1;
    bf16x8 fr;
#pragma unroll
    for (int r = 0; r < 4; ++r) { fr[r] = f2bf(acc[0][r]); fr[4 + r] = f2bf(acc[1][r]); }
    *(bf16x8*)(Qp + (((size_t)hh * (NE / 16) + it_g) * 2 + kc) * 512 + (size_t)lane * 8) = fr;
  } else {
    const int bb = blockIdx.x - 512;
    const int RT0 = (bb & 63) * 4;
    const int CT0 = (bb >> 6) * 4;

#define KVSTAGE(buf, kt)                                                       \
  do {                                                                         \
    gl_lds16(X2 + ((size_t)((RT0 + w) * 16 + (kt)) * 64 + lane) * 8,           \
             &tiles[buf][w * 512 + lane * 8]);                                 \
    gl_lds16(Wkf + ((size_t)((CT0 + w) * 16 + (kt)) * 64 + lane) * 8,          \
             &tiles[buf][(4 + w) * 512 + lane * 8]);                           \
    gl_lds16(Wvf + ((size_t)((CT0 + w) * 16 + (kt)) * 64 + lane) * 8,          \
             &tiles[buf][(8 + w) * 512 + lane * 8]);                           \
  } while (0)

    const int wr = w >> 1, wc = w & 1;
    f32x4 accK[2][2], accV[2][2];
#pragma unroll
    for (int a = 0; a < 2; ++a)
#pragma unroll
      for (int b = 0; b < 2; ++b) {
        accK[a][b] = (f32x4){0.f, 0.f, 0.f, 0.f};
        accV[a][b] = (f32x4){0.f, 0.f, 0.f, 0.f};
      }

    KVSTAGE(0, 0);
    for (int kt = 0; kt < 16; ++kt) {
      const int cb = kt & 1;
      if (kt + 1 < 16) {
        KVSTAGE(cb ^ 1, kt + 1);
        asm volatile("s_waitcnt vmcnt(3)" ::: "memory");
      } else {
        asm volatile("s_waitcnt vmcnt(0)" ::: "memory");
      }
      __builtin_amdgcn_s_barrier();
      bf16x8 xf[2], kf[2], vf[2];
#pragma unroll
      for (int p = 0; p < 2; ++p) {
        xf[p] = *(const bf16x8*)&tiles[cb][(wr * 2 + p) * 512 + lane * 8];
        kf[p] = *(const bf16x8*)&tiles[cb][(4 + wc * 2 + p) * 512 + lane * 8];
        vf[p] = *(const bf16x8*)&tiles[cb][(8 + wc * 2 + p) * 512 + lane * 8];
      }
#pragma unroll
      for (int ci = 0; ci < 2; ++ci)
#pragma unroll
        for (int ji = 0; ji < 2; ++ji) {
          accK[ci][ji] = __builtin_amdgcn_mfma_f32_16x16x32_bf16(kf[ci], xf[ji], accK[ci][ji], 0, 0, 0);
          accV[ji][ci] = __builtin_amdgcn_mfma_f32_16x16x32_bf16(xf[ji], vf[ci], accV[ji][ci], 0, 0, 0);
        }
      __builtin_amdgcn_s_barrier();
    }

    const int ct_even = CT0 + wc * 2;
    const int hh = ct_even >> 2, kc = (ct_even >> 1) & 1;
#pragma unroll
    for (int ji = 0; ji < 2; ++ji) {
      const int jt16 = RT0 + wr * 2 + ji;
      bf16x8 fr;
#pragma unroll
      for (int r = 0; r < 4; ++r) { fr[r] = f2bf(accK[0][ji][r]); fr[4 + r] = f2bf(accK[1][ji][r]); }
      *(bf16x8*)(Kp + (((((size_t)hh * 64 + (jt16 >> 2)) * 4 + (jt16 & 3)) * 2 + kc) * 512) + (size_t)lane * 8) = fr;
    }
    const int jt_even = RT0 + wr * 2;
    const int jt64 = jt_even >> 2, kcv = (jt_even >> 1) & 1;
#pragma unroll
    for (int ci = 0; ci < 2; ++ci) {
      const int ctg = CT0 + wc * 2 + ci;
      const int hhv = ctg >> 2, dh16 = ctg & 3;
      bf16x8 fr;
#pragma unroll
      for (int r = 0; r < 4; ++r) { fr[r] = f2bf(accV[0][ci][r]); fr[4 + r] = f2bf(accV[1][ci][r]); }
      *(bf16x8*)(Vp + ((((size_t)hhv * 64 + jt64) * 4 + dh16) * 2 + kcv) * 512 + (size_t)lane * 8) = fr;
    }
  }
}

// ---------- fused MFMA attention (round-15 best: LDS dbuf, bf16 po) ----------
__global__ __launch_bounds__(256) void attn_mfma(
    const short* __restrict__ Qp, const short* __restrict__ Kp,
    const short* __restrict__ Vp, const unsigned short* __restrict__ maskb,
    const float* __restrict__ rel_emb, float* __restrict__ scores,
    short* __restrict__ po, float* __restrict__ pm, float* __restrict__ pl,
    int tps) {
  const int h = blockIdx.y;
  const int split = blockIdx.z;
  const int tid = threadIdx.x;
  const int wid = tid >> 6;
  const int lane = tid & 63;
  const int i0w = blockIdx.x * 64 + wid * 16;
  const int gi = i0w + (lane & 15);
  const int gi15 = lane & 15;
  const int lhi4 = (lane >> 4) * 4;
  const int jt0 = split * tps;
  const int itw = i0w >> 4;

  __shared__ __align__(16) short Kt[2][4096];
  __shared__ __align__(16) short Vt[2][4096];
  __shared__ __align__(16) unsigned short Ms[4][2][64];
  __shared__ float relb[NREL];

  if (tid < NREL) relb[tid] = rel_emb[tid * H + h];
  __syncthreads();

  const size_t qbase = (((size_t)h * (NE / 16) + itw) * 2) * 512 + (size_t)lane * 8;
  const bf16x8 qf0 = *(const bf16x8*)(Qp + qbase);
  const bf16x8 qf1 = *(const bf16x8*)(Qp + qbase + 512);

  const short* kgh = Kp + (size_t)h * 64 * 4096;
  const short* vgh = Vp + (size_t)h * 64 * 4096;
  const unsigned short* mgh = maskb + (size_t)itw * NN;

#define STAGE(buf, jt)                                              \
  do {                                                              \
    const short* kg_ = kgh + (size_t)(jt) * 4096 + tid * 8;         \
    const short* vg_ = vgh + (size_t)(jt) * 4096 + tid * 8;         \
    gl_lds16(kg_, &Kt[buf][tid * 8]);                               \
    gl_lds16(kg_ + 2048, &Kt[buf][2048 + tid * 8]);                 \
    gl_lds16(vg_, &Vt[buf][tid * 8]);                               \
    gl_lds16(vg_ + 2048, &Vt[buf][2048 + tid * 8]);                 \
    if (lane < 8)                                                   \
      gl_lds16(mgh + (size_t)(jt) * 64 + lane * 8,                  \
               &Ms[wid][buf][lane * 8]);                            \
  } while (0)

  STAGE(0, jt0);
  asm volatile("s_waitcnt vmcnt(0)" ::: "memory");
  __builtin_amdgcn_s_barrier();

  float m_run = -INFINITY, l_run = 0.f;
  f32x4 o0 = {0.f, 0.f, 0.f, 0.f}, o1 = o0, o2 = o0, o3 = o0;

  for (int t = 0; t < tps; ++t) {
    const int jb = jt0 + t;
    const int b = t & 1;
    if (t + 1 < tps) {
      STAGE(b ^ 1, jb + 1);
      if (t > 0) { asm volatile("s_waitcnt vmcnt(9)" ::: "memory"); }
    } else {
      if (t > 0) { asm volatile("s_waitcnt vmcnt(4)" ::: "memory"); }
    }
    __builtin_amdgcn_s_barrier();

    const int j0 = jb * 64;
    const float bc0 = relb[0], bc20 = relb[20];
    const bool allhi = (j0 > i0w + 15 + MAXREL);
    const bool alllo = (j0 + 63 < i0w - MAXREL);

    float lg[4][4];
#pragma unroll
    for (int ms = 0; ms < 4; ++ms) {
      const bf16x8 ka = *(const bf16x8*)&Kt[b][(ms * 2 + 0) * 512 + lane * 8];
      const bf16x8 kb = *(const bf16x8*)&Kt[b][(ms * 2 + 1) * 512 + lane * 8];
      f32x4 sf = {0.f, 0.f, 0.f, 0.f};
      __builtin_amdgcn_s_setprio(1);
      sf = __builtin_amdgcn_mfma_f32_16x16x32_bf16(ka, qf0, sf, 0, 0, 0);
      sf = __builtin_amdgcn_mfma_f32_16x16x32_bf16(kb, qf1, sf, 0, 0, 0);
      __builtin_amdgcn_s_setprio(0);
      const int jb0 = j0 + ms * 16 + lhi4;
      const uint2 mw = *(const uint2*)&Ms[wid][b][ms * 16 + lhi4];
#pragma unroll
      for (int r = 0; r < 4; ++r) {
        const int gj = jb0 + r;
        float bias;
        if (allhi) bias = bc0;
        else if (alllo) bias = bc20;
        else {
          int dd = gi - gj;
          dd = dd < -MAXREL ? -MAXREL : (dd > MAXREL ? MAXREL : dd);
          bias = relb[dd + MAXREL];
        }
        const unsigned word = (r < 2) ? mw.x : mw.y;
        const unsigned ok = (word >> ((r & 1) * 16 + gi15)) & 1u;
        lg[ms][r] = ok ? fmaf(sf[r], 0.125f, bias) : -INFINITY;
      }
      f32x4 sv;
      sv[0] = fmaxf(lg[ms][0], NEG_BIG);
      sv[1] = fmaxf(lg[ms][1], NEG_BIG);
      sv[2] = fmaxf(lg[ms][2], NEG_BIG);
      sv[3] = fmaxf(lg[ms][3], NEG_BIG);
      *(f32x4*)(scores + ((size_t)h * NE + gi) * NN + jb0) = sv;
    }

    float tmax = -INFINITY;
#pragma unroll
    for (int ms = 0; ms < 4; ++ms)
#pragma unroll
      for (int r = 0; r < 4; ++r) tmax = fmaxf(tmax, lg[ms][r]);
    tmax = fmaxf(tmax, __shfl_xor(tmax, 16));
    tmax = fmaxf(tmax, __shfl_xor(tmax, 32));
    const float mnew = fmaxf(m_run, tmax);
    const float rs = (m_run == mnew) ? 1.f : exp2f((m_run - mnew) * L2E);
    float p[4][4];
    float ps = 0.f;
#pragma unroll
    for (int ms = 0; ms < 4; ++ms)
#pragma unroll
      for (int r = 0; r < 4; ++r) {
        const float v = lg[ms][r];
        const float pe = (v == -INFINITY) ? 0.f : exp2f((v - mnew) * L2E);
        p[ms][r] = pe;
        ps += pe;
      }
    l_run = l_run * rs + ps;
    m_run = mnew;
    if (!__all(rs == 1.0f)) { o0 *= rs; o1 *= rs; o2 *= rs; o3 *= rs; }

    bf16x8 pb0, pb1;
    pb0[0] = f2bf_t(p[0][0]); pb0[1] = f2bf_t(p[0][1]); pb0[2] = f2bf_t(p[0][2]); pb0[3] = f2bf_t(p[0][3]);
    pb0[4] = f2bf_t(p[1][0]); pb0[5] = f2bf_t(p[1][1]); pb0[6] = f2bf_t(p[1][2]); pb0[7] = f2bf_t(p[1][3]);
    pb1[0] = f2bf_t(p[2][0]); pb1[1] = f2bf_t(p[2][1]); pb1[2] = f2bf_t(p[2][2]); pb1[3] = f2bf_t(p[2][3]);
    pb1[4] = f2bf_t(p[3][0]); pb1[5] = f2bf_t(p[3][1]); pb1[6] = f2bf_t(p[3][2]); pb1[7] = f2bf_t(p[3][3]);

    __builtin_amdgcn_s_setprio(1);
    o0 = __builtin_amdgcn_mfma_f32_16x16x32_bf16(*(const bf16x8*)&Vt[b][0 * 512 + lane * 8], pb0, o0, 0, 0, 0);
    o0 = __builtin_amdgcn_mfma_f32_16x16x32_bf16(*(const bf16x8*)&Vt[b][1 * 512 + lane * 8], pb1, o0, 0, 0, 0);
    o1 = __builtin_amdgcn_mfma_f32_16x16x32_bf16(*(const bf16x8*)&Vt[b][2 * 512 + lane * 8], pb0, o1, 0, 0, 0);
    o1 = __builtin_amdgcn_mfma_f32_16x16x32_bf16(*(const bf16x8*)&Vt[b][3 * 512 + lane * 8], pb1, o1, 0, 0, 0);
    o2 = __builtin_amdgcn_mfma_f32_16x16x32_bf16(*(const bf16x8*)&Vt[b][4 * 512 + lane * 8], pb0, o2, 0, 0, 0);
    o2 = __builtin_amdgcn_mfma_f32_16x16x32_bf16(*(const bf16x8*)&Vt[b][5 * 512 + lane * 8], pb1, o2, 0, 0, 0);
    o3 = __builtin_amdgcn_mfma_f32_16x16x32_bf16(*(const bf16x8*)&Vt[b][6 * 512 + lane * 8], pb0, o3, 0, 0, 0);
    o3 = __builtin_amdgcn_mfma_f32_16x16x32_bf16(*(const bf16x8*)&Vt[b][7 * 512 + lane * 8], pb1, o3, 0, 0, 0);
    __builtin_amdgcn_s_setprio(0);

    asm volatile("s_waitcnt lgkmcnt(0)" ::: "memory");
    __builtin_amdgcn_s_barrier();
  }

  l_run += __shfl_xor(l_run, 16);
  l_run += __shfl_xor(l_run, 32);
  const size_t pbase = ((size_t)split * H + h) * NE + gi;
  if (lane < 16) { pm[pbase] = m_run; pl[pbase] = l_run; }
  short* pob = po + pbase * DH + lhi4;
  *(short4*)(pob +  0) = make_short4(f2bf(o0[0]), f2bf(o0[1]), f2bf(o0[2]), f2bf(o0[3]));
  *(short4*)(pob + 16) = make_short4(f2bf(o1[0]), f2bf(o1[1]), f2bf(o1[2]), f2bf(o1[3]));
  *(short4*)(pob + 32) = make_short4(f2bf(o2[0]), f2bf(o2[1]), f2bf(o2[2]), f2bf(o2[3]));
  *(short4*)(pob + 48) = make_short4(f2bf(o3[0]), f2bf(o3[1]), f2bf(o3[2]), f2bf(o3[3]));
}

// ---------- combine: merge split partials + silu -> Rf att-part (bf16 frags) ----------
__global__ __launch_bounds__(256) void combine_kernel(
    const short* __restrict__ po, const float* __restrict__ pm,
    const float* __restrict__ pl, short* __restrict__ Rf, int splits) {
  const int g = blockIdx.x * 8 + (threadIdx.x >> 5);
  const int dh0 = (threadIdx.x & 31) * 2;
  const int h = g >> 11;
  const int i = g & (NE - 1);
  float M = -INFINITY;
  for (int s = 0; s < splits; ++s)
    M = fmaxf(M, pm[((size_t)s * H + h) * NE + i]);
  float L = 0.f, o0 = 0.f, o1 = 0.f;
  for (int s = 0; s < splits; ++s) {
    const size_t pb = ((size_t)s * H + h) * NE + i;
    const float ms = pm[pb];
    if (ms > -INFINITY) {
      const float wgt = exp2f((ms - M) * L2E);
      L += wgt * pl[pb];
      const short2 ov = *(const short2*)&po[pb * DH + dh0];
      o0 += wgt * bf2f(ov.x);
      o1 += wgt * bf2f(ov.y);
    }
  }
  const float a0 = o0 / L, a1 = o1 / L;
  const float s0 = a0 / (1.f + expf(-a0));
  const float s1 = a1 / (1.f + expf(-a1));
  const int col = 256 + h * DH + dh0;
  const int kt = col >> 5, kk = col & 31;
  const int l = ((kk >> 2) & 3) * 16 + (i & 15);
  const int ee = (kk >> 4) * 4 + (kk & 3);
  short* dst = Rf + ((size_t)((i >> 4) * 24 + kt) * 64 + l) * 8 + ee;
  *(short2*)dst = make_short2(f2bf(s0), f2bf(s1));
}

// ---------- final GEMM (MFMA): out = Rf[2048x768] @ Wo + bo ----------
__global__ __launch_bounds__(256) void final_mfma(
    const short* __restrict__ Rf, const short* __restrict__ Wof,
    const float* __restrict__ bo, float* __restrict__ out) {
  const int tid = threadIdx.x;
  const int w = tid >> 6, lane = tid & 63;
  const int RT0 = blockIdx.x * 2;
  const int CT0 = blockIdx.y * 4;
  __shared__ __align__(16) short tiles[2][12 * 512];

#define FSTAGE(buf, ks)                                                        \
  do {                                                                         \
    const int rtl_ = w >> 1, ktl_ = w & 1;                                     \
    gl_lds16(Rf + ((size_t)((RT0 + rtl_) * 24 + (ks) * 2 + ktl_) * 64 + lane) * 8, \
             &tiles[buf][w * 512 + lane * 8]);                                 \
    gl_lds16(Wof + ((size_t)((CT0 + (w >> 1)) * 24 + (ks) * 2 + (w & 1)) * 64 + lane) * 8, \
             &tiles[buf][(4 + w) * 512 + lane * 8]);                           \
    gl_lds16(Wof + ((size_t)((CT0 + 2 + (w >> 1)) * 24 + (ks) * 2 + (w & 1)) * 64 + lane) * 8, \
             &tiles[buf][(8 + w) * 512 + lane * 8]);                           \
  } while (0)

  const int itl = w >> 1, ctp = w & 1;
  f32x4 acc[2] = {{0.f, 0.f, 0.f, 0.f}, {0.f, 0.f, 0.f, 0.f}};

  FSTAGE(0, 0);
  for (int ks = 0; ks < 12; ++ks) {
    const int cb = ks & 1;
    if (ks + 1 < 12) {
      FSTAGE(cb ^ 1, ks + 1);
      asm volatile("s_waitcnt vmcnt(3)" ::: "memory");
    } else {
      asm volatile("s_waitcnt vmcnt(0)" ::: "memory");
    }
    __builtin_amdgcn_s_barrier();
#pragma unroll
    for (int ktl = 0; ktl < 2; ++ktl) {
      const bf16x8 rf = *(const bf16x8*)&tiles[cb][(itl * 2 + ktl) * 512 + lane * 8];
#pragma unroll
      for (int ci = 0; ci < 2; ++ci) {
        const int ctl = ctp * 2 + ci;
        const bf16x8 wf = *(const bf16x8*)&tiles[cb][(4 + ctl * 2 + ktl) * 512 + lane * 8];
        acc[ci] = __builtin_amdgcn_mfma_f32_16x16x32_bf16(wf, rf, acc[ci], 0, 0, 0);
      }
    }
    __builtin_amdgcn_s_barrier();
  }

  const int gi = (RT0 + itl) * 16 + (lane & 15);
  const int lhi4 = (lane >> 4) * 4;
#pragma unroll
  for (int ci = 0; ci < 2; ++ci) {
    const int c0 = (CT0 + ctp * 2 + ci) * 16 + lhi4;
    float4 o;
    o.x = acc[ci][0] + bo[c0];
    o.y = acc[ci][1] + bo[c0 + 1];
    o.z = acc[ci][2] + bo[c0 + 2];
    o.w = acc[ci][3] + bo[c0 + 3];
    *(float4*)(out + (size_t)gi * D + c0) = o;
  }
}

extern "C" void kernel_launch(void* const* d_in, const int* in_sizes, int n_in,
                              void* d_out, int out_size, void* d_ws, size_t ws_size,
                              hipStream_t stream) {
  (void)in_sizes; (void)n_in; (void)out_size;
  const float* he   = (const float*)d_in[0];
  const float* nf   = (const float*)d_in[1];
  const int*   inc  = (const int*)d_in[2];
  const int*   ntyp = (const int*)d_in[3];
  const int*   htyp = (const int*)d_in[4];
  const float* Wq   = (const float*)d_in[5];
  const float* Wk   = (const float*)d_in[6];
  const float* Wv   = (const float*)d_in[7];
  const float* Wo   = (const float*)d_in[8];
  const float* bo   = (const float*)d_in[9];
  const float* ge   = (const float*)d_in[10];
  const float* be   = (const float*)d_in[11];
  const float* gn   = (const float*)d_in[12];
  const float* bn   = (const float*)d_in[13];
  const float* rel  = (const float*)d_in[14];

  float* outf = (float*)d_out;
  float* outs = outf + (size_t)NE * D;

  short* X2   = (short*)d_ws;
  short* E2   = X2 + (size_t)NN * 512;
  short* Wkf  = E2 + (size_t)NE * 1024;
  short* Wvf  = Wkf + (size_t)512 * 512;
  short* Wqf  = Wvf + (size_t)512 * 512;
  short* Qp   = Wqf + (size_t)512 * 1024;
  short* Kp   = Qp + (size_t)NE * HD;
  short* Vp   = Kp + (size_t)NN * HD;
  short* Rf   = Vp + (size_t)NN * HD;
  short* Wof  = Rf + (size_t)128 * 24 * 512;
  unsigned short* maskb = (unsigned short*)(Wof + (size_t)384 * 512);
  short* po   = (short*)(maskb + (size_t)(NE / 16) * NN);

  const size_t used_bytes = (size_t)((char*)po - (char*)d_ws);
  int splits = 8;
  while (splits > 1 &&
         used_bytes + (size_t)splits * H * NE * (DH * 2 + 8) > ws_size)
    splits >>= 1;
  float* pm = (float*)(po + (size_t)splits * H * NE * DH);
  float* pl = pm + (size_t)splits * H * NE;
  const int tps = NN / 64 / splits;

  prep_all<<<NE + NN + NN / 2 + 256 + 128 + 96, 256, 0, stream>>>(
      he, htyp, ge, be, nf, ntyp, gn, bn, inc, Wq, Wk, Wv, Wo,
      E2, X2, maskb, Wqf, Wkf, Wvf, Rf, Wof);
  proj_all<<<1024, 256, 0, stream>>>(E2, Wqf, Qp, X2, Wkf, Wvf, Kp, Vp);
  attn_mfma<<<dim3(NE / 64, H, splits), 256, 0, stream>>>(
      Qp, Kp, Vp, maskb, rel, outs, po, pm, pl, tps);
  combine_kernel<<<NE * H / 8, 256, 0, stream>>>(po, pm, pl, Rf, splits);
  final_mfma<<<dim3(64, 4), 256, 0, stream>>>(Rf, Wof, bo, outf);
}